// Round 20
// baseline (634.742 us; speedup 1.0000x reference)
//
#include <hip/hip_runtime.h>
#include <math.h>

#define BSZ   32768
#define DD    512
#define HH    128
#define NN    1000
#define TM    32
#define NBLK  (BSZ / TM)   // 1024
#define FBTM  16
#define FBBLK (BSZ / FBTM) // 2048

typedef short  bf8 __attribute__((ext_vector_type(8)));
typedef float  f4  __attribute__((ext_vector_type(4)));

__device__ __forceinline__ unsigned short cv20_f2bf(float f) {
    unsigned u = __float_as_uint(f);
    u = u + 0x7FFF + ((u >> 16) & 1);
    return (unsigned short)(u >> 16);
}
__device__ __forceinline__ float cv20_bf2f(unsigned short h) {
    return __uint_as_float(((unsigned)h) << 16);
}

#define MFMA16(a, b, c) __builtin_amdgcn_mfma_f32_16x16x32_bf16((a), (b), (c), 0, 0, 0)

// ---------- pre-kernels (validated r15-r19) ----------
__global__ void cv20_prep_txt(const float* __restrict__ txt,
                              unsigned short* __restrict__ th,
                              unsigned short* __restrict__ tl)
{
    int j = blockIdx.x;                       // 0..1023, zero-padded
    for (int k = threadIdx.x; k < DD; k += blockDim.x) {
        float v = (j < NN) ? txt[(size_t)k * NN + j] : 0.f;
        unsigned short h = cv20_f2bf(v);
        unsigned short l = cv20_f2bf(v - cv20_bf2f(h));
        th[(size_t)j * DD + k] = h;
        tl[(size_t)j * DD + k] = l;
    }
}
__global__ void cv20_prep_w1(const float* __restrict__ w1,
                             unsigned short* __restrict__ th,
                             unsigned short* __restrict__ tl)
{
    int j = blockIdx.x;                       // 0..127
    for (int k = threadIdx.x; k < DD; k += blockDim.x) {
        float v = w1[(size_t)k * HH + j];
        unsigned short h = cv20_f2bf(v);
        unsigned short l = cv20_f2bf(v - cv20_bf2f(h));
        th[(size_t)j * DD + k] = h;
        tl[(size_t)j * DD + k] = l;
    }
}
__global__ void cv20_prep_w2(const float* __restrict__ w2,
                             unsigned short* __restrict__ th,
                             unsigned short* __restrict__ tl)
{
    int j = blockIdx.x;                       // 0..511
    for (int k = threadIdx.x; k < HH; k += blockDim.x) {
        float v = w2[(size_t)k * DD + j];
        unsigned short h = cv20_f2bf(v);
        unsigned short l = cv20_f2bf(v - cv20_bf2f(h));
        th[(size_t)j * HH + k] = h;
        tl[(size_t)j * HH + k] = l;
    }
}

// ---------- main: TM=32, 16 waves (2 rg x 8 cg), 128-VGPR budget (no spill) ----------
__global__ __launch_bounds__(1024, 4)
void cv20_main(const float* __restrict__ img,
               const float* __restrict__ b1,
               const float* __restrict__ b2,
               const unsigned short* __restrict__ txtTh,
               const unsigned short* __restrict__ txtTl,
               const unsigned short* __restrict__ w1Th,
               const unsigned short* __restrict__ w1Tl,
               const unsigned short* __restrict__ w2Th,
               const unsigned short* __restrict__ w2Tl,
               const unsigned* __restrict__ target,
               float* __restrict__ partials)
{
    __shared__ unsigned short YH[2][16 * 512];   // 32 KB A-frag hi per row-group
    __shared__ unsigned short YL[2][16 * 512];   // 32 KB A-frag lo
    __shared__ float red[1024];
    __shared__ float sAr[TM], sMx[TM], sVt[TM];
    __shared__ float srow[TM][2];
    __shared__ int   stgt[TM];
    __shared__ int   tflag;

    unsigned short* hfH = &YH[0][0];       // alias; barriers separate lifetimes
    unsigned short* hfL = &YH[0][4096];

    const int t    = threadIdx.x;
    const int w    = t >> 6;        // wave 0..15
    const int l    = t & 63;
    const int wr   = w >> 3;        // row-group 0/1
    const int wc   = w & 7;         // col-group 0..7
    const int blk  = blockIdx.x;
    const int row0 = blk * TM;

    if (t == 0) {
        int allz = 1, small = 1;
        #pragma unroll 1
        for (int i = 0; i < 32; ++i) {
            allz  &= (target[2 * i + 1] == 0u);
            small &= (target[2 * i] < 1000000u);
        }
        tflag = (allz && small) ? 1 : 0;
    }
    __syncthreads();
    if (t < TM) {
        int r = row0 + t;
        int tg = (int)(tflag ? target[2 * r] : target[r]);
        if (tg < 0) tg = 0;
        if (tg > NN - 1) tg = NN - 1;
        stgt[t] = tg;
    }

    // P1: pack img A-fragments from global (2 k-tiles per wave) [r17-validated]
    #pragma unroll
    for (int s = 0; s < 2; ++s) {
        const int kt = wc * 2 + s;
        const float* ip = img + (size_t)(row0 + wr * 16 + (l & 15)) * DD + kt * 32 + (l >> 4) * 8;
        float4 v0 = *(const float4*)ip;
        float4 v1 = *(const float4*)(ip + 4);
        float xs[8] = {v0.x, v0.y, v0.z, v0.w, v1.x, v1.y, v1.z, v1.w};
        bf8 vh, vl;
        #pragma unroll
        for (int e = 0; e < 8; ++e) {
            unsigned short hh = cv20_f2bf(xs[e]);
            vh[e] = (short)hh;
            vl[e] = (short)cv20_f2bf(xs[e] - cv20_bf2f(hh));
        }
        *(bf8*)&YH[wr][kt * 512 + l * 8] = vh;
        *(bf8*)&YL[wr][kt * 512 + l * 8] = vl;
    }
    __syncthreads();

    // P2: h = relu(img @ w1 + b1) [r17-validated]
    float hv[4];
    {
        f4 acc = {0.f, 0.f, 0.f, 0.f};
        const int jj = wc * 16 + (l & 15);
        const unsigned short* bh = w1Th + (size_t)jj * DD + ((l >> 4) * 8);
        const unsigned short* bl = w1Tl + (size_t)jj * DD + ((l >> 4) * 8);
        #pragma unroll 4
        for (int kt = 0; kt < 16; ++kt) {
            bf8 ah = *(const bf8*)&YH[wr][kt * 512 + l * 8];
            bf8 al = *(const bf8*)&YL[wr][kt * 512 + l * 8];
            bf8 wh = *(const bf8*)(bh + kt * 32);
            bf8 wl = *(const bf8*)(bl + kt * 32);
            acc = MFMA16(ah, wh, acc);
            acc = MFMA16(ah, wl, acc);
            acc = MFMA16(al, wh, acc);
        }
        float bv = b1[jj];
        #pragma unroll
        for (int r = 0; r < 4; ++r) hv[r] = fmaxf(acc[r] + bv, 0.f);
    }
    __syncthreads();

    // P2b: scatter h into hf fragment layout [r17-validated]
    {
        const int jj  = wc * 16 + (l & 15);
        const int kt2 = jj >> 5;
        const int e   = jj & 7;
        const int hi4 = ((jj >> 3) & 3) << 4;
        #pragma unroll
        for (int r = 0; r < 4; ++r) {
            int row16 = (l >> 4) * 4 + r;
            int lane2 = row16 | hi4;
            unsigned short hh = cv20_f2bf(hv[r]);
            hfH[wr * 2048 + kt2 * 512 + lane2 * 8 + e] = hh;
            hfL[wr * 2048 + kt2 * 512 + lane2 * 8 + e] = cv20_f2bf(hv[r] - cv20_bf2f(hh));
        }
    }
    __syncthreads();

    // P3: adapted = relu(h @ w2 + b2); blend with img re-read [r17-validated]
    float blv[4][4];
    {
        const int c15 = l & 15;
        #pragma unroll
        for (int ti = 0; ti < 4; ++ti) {
            const int tix = wc + ti * 8;
            const int jj  = tix * 16 + c15;
            f4 acc = {0.f, 0.f, 0.f, 0.f};
            const unsigned short* bh = w2Th + (size_t)jj * HH + ((l >> 4) * 8);
            const unsigned short* bl = w2Tl + (size_t)jj * HH + ((l >> 4) * 8);
            #pragma unroll
            for (int kt = 0; kt < 4; ++kt) {
                bf8 ah = *(const bf8*)&hfH[wr * 2048 + kt * 512 + l * 8];
                bf8 al = *(const bf8*)&hfL[wr * 2048 + kt * 512 + l * 8];
                bf8 wh = *(const bf8*)(bh + kt * 32);
                bf8 wl = *(const bf8*)(bl + kt * 32);
                acc = MFMA16(ah, wh, acc);
                acc = MFMA16(ah, wl, acc);
                acc = MFMA16(al, wh, acc);
            }
            float bv = b2[jj];
            #pragma unroll
            for (int r = 0; r < 4; ++r) {
                int row16 = (l >> 4) * 4 + r;
                float iv = img[(size_t)(row0 + wr * 16 + row16) * DD + jj];
                blv[ti][r] = 0.5f * iv + 0.5f * fmaxf(acc[r] + bv, 0.f);
            }
        }
    }
    __syncthreads();

    // P3b: scatter img_adapted into YH/YL [r17-validated]
    {
        const int c15 = l & 15;
        #pragma unroll
        for (int ti = 0; ti < 4; ++ti) {
            const int tix = wc + ti * 8;
            const int jj  = tix * 16 + c15;
            const int kt  = jj >> 5;
            const int e   = jj & 7;
            const int hi4 = ((jj >> 3) & 3) << 4;
            #pragma unroll
            for (int r = 0; r < 4; ++r) {
                int row16 = (l >> 4) * 4 + r;
                int lane2 = row16 | hi4;
                unsigned short hh = cv20_f2bf(blv[ti][r]);
                YH[wr][kt * 512 + lane2 * 8 + e] = hh;
                YL[wr][kt * 512 + lane2 * 8 + e] = cv20_f2bf(blv[ti][r] - cv20_bf2f(hh));
            }
        }
    }
    __syncthreads();

    // P4: sim tiles in registers; 8 tiles/wave, 2 interleaved chains [r17-validated]
    f4 simacc[8];
    #pragma unroll
    for (int i = 0; i < 8; ++i) simacc[i] = (f4){0.f, 0.f, 0.f, 0.f};

    #pragma unroll
    for (int tp = 0; tp < 4; ++tp) {
        const int tixA = wc + tp * 16;
        const int tixB = tixA + 8;
        const unsigned short* bhA = txtTh + (size_t)(tixA * 16 + (l & 15)) * DD + ((l >> 4) * 8);
        const unsigned short* blA = txtTl + (size_t)(tixA * 16 + (l & 15)) * DD + ((l >> 4) * 8);
        const unsigned short* bhB = txtTh + (size_t)(tixB * 16 + (l & 15)) * DD + ((l >> 4) * 8);
        const unsigned short* blB = txtTl + (size_t)(tixB * 16 + (l & 15)) * DD + ((l >> 4) * 8);
        #pragma unroll 4
        for (int kt = 0; kt < 16; ++kt) {
            bf8 ah  = *(const bf8*)&YH[wr][kt * 512 + l * 8];
            bf8 al  = *(const bf8*)&YL[wr][kt * 512 + l * 8];
            bf8 wAh = *(const bf8*)(bhA + kt * 32);
            bf8 wAl = *(const bf8*)(blA + kt * 32);
            bf8 wBh = *(const bf8*)(bhB + kt * 32);
            bf8 wBl = *(const bf8*)(blB + kt * 32);
            simacc[tp * 2]     = MFMA16(ah, wAh, simacc[tp * 2]);
            simacc[tp * 2 + 1] = MFMA16(ah, wBh, simacc[tp * 2 + 1]);
            simacc[tp * 2]     = MFMA16(ah, wAl, simacc[tp * 2]);
            simacc[tp * 2 + 1] = MFMA16(ah, wBl, simacc[tp * 2 + 1]);
            simacc[tp * 2]     = MFMA16(al, wAh, simacc[tp * 2]);
            simacc[tp * 2 + 1] = MFMA16(al, wBh, simacc[tp * 2 + 1]);
        }
    }

    // ---- epilogue from registers [r17-validated] ----
    float s2v[4] = {0.f, 0.f, 0.f, 0.f};
    float mxv[4] = {-1e30f, -1e30f, -1e30f, -1e30f};
    float vtv[4] = {-1e30f, -1e30f, -1e30f, -1e30f};
    int   mxi[4] = {0x7fffffff, 0x7fffffff, 0x7fffffff, 0x7fffffff};

    #pragma unroll
    for (int i = 0; i < 8; ++i) {
        const int tix = wc + (i >> 1) * 16 + (i & 1) * 8;
        const int col = tix * 16 + (l & 15);
        const bool ok = col < NN;
        #pragma unroll
        for (int r = 0; r < 4; ++r) {
            float v = simacc[i][r];
            if (ok) {
                s2v[r] += v * v;
                if (v > mxv[r] || (v == mxv[r] && col < mxi[r])) { mxv[r] = v; mxi[r] = col; }
                int R = wr * 16 + (l >> 4) * 4 + r;
                if (col == stgt[R]) vtv[r] = v;
            }
        }
    }
    #pragma unroll
    for (int m = 1; m < 16; m <<= 1) {
        #pragma unroll
        for (int r = 0; r < 4; ++r) {
            s2v[r] += __shfl_xor(s2v[r], m);
            float ov = __shfl_xor(mxv[r], m);
            int   oi = __shfl_xor(mxi[r], m);
            if (ov > mxv[r] || (ov == mxv[r] && oi < mxi[r])) { mxv[r] = ov; mxi[r] = oi; }
            vtv[r] = fmaxf(vtv[r], __shfl_xor(vtv[r], m));
        }
    }
    if ((l & 15) == 0) {
        #pragma unroll
        for (int r = 0; r < 4; ++r) {
            int R = wr * 16 + (l >> 4) * 4 + r;
            red[  0 + R * 8 + wc] = s2v[r];
            red[256 + R * 8 + wc] = mxv[r];
            red[512 + R * 8 + wc] = __int_as_float(mxi[r]);
            red[768 + R * 8 + wc] = vtv[r];
        }
    }
    __syncthreads();
    if (t < TM) {
        float S2 = 0.f, MX = -1e30f, VT = -1e30f;
        int MI = 0x7fffffff;
        #pragma unroll
        for (int ww = 0; ww < 8; ++ww) {
            S2 += red[t * 8 + ww];
            float ov = red[256 + t * 8 + ww];
            int   oi = __float_as_int(red[512 + t * 8 + ww]);
            if (ov > MX || (ov == MX && oi < MI)) { MX = ov; MI = oi; }
            VT = fmaxf(VT, red[768 + t * 8 + ww]);
        }
        sAr[t] = 1.0f / sqrtf(S2);
        sMx[t] = MX;
        sVt[t] = VT;
        srow[t][1] = (MI == stgt[t]) ? 1.f : 0.f;
    }
    __syncthreads();

    float es[4] = {0.f, 0.f, 0.f, 0.f};
    #pragma unroll
    for (int i = 0; i < 8; ++i) {
        const int tix = wc + (i >> 1) * 16 + (i & 1) * 8;
        const int col = tix * 16 + (l & 15);
        const bool ok = col < NN;
        #pragma unroll
        for (int r = 0; r < 4; ++r) {
            if (ok) {
                int R = wr * 16 + (l >> 4) * 4 + r;
                es[r] += expf((simacc[i][r] - sMx[R]) * sAr[R]);
            }
        }
    }
    #pragma unroll
    for (int m = 1; m < 16; m <<= 1) {
        #pragma unroll
        for (int r = 0; r < 4; ++r) es[r] += __shfl_xor(es[r], m);
    }
    if ((l & 15) == 0) {
        #pragma unroll
        for (int r = 0; r < 4; ++r) {
            int R = wr * 16 + (l >> 4) * 4 + r;
            red[R * 8 + wc] = es[r];
        }
    }
    __syncthreads();
    if (t < TM) {
        float E = 0.f;
        #pragma unroll
        for (int ww = 0; ww < 8; ++ww) E += red[t * 8 + ww];
        srow[t][0] = (sMx[t] - sVt[t]) * sAr[t] + logf(E);
    }
    __syncthreads();
    if (t == 0) {
        float ls = 0.f, ac = 0.f;
        #pragma unroll
        for (int r = 0; r < TM; ++r) { ls += srow[r][0]; ac += srow[r][1]; }
        partials[blk * 2 + 0] = ls;
        partials[blk * 2 + 1] = ac;
    }
}

__global__ __launch_bounds__(256)
void cv20_final(const float* __restrict__ partials, int nblk, float* __restrict__ out)
{
    __shared__ float fb[512];
    float ls = 0.f, ac = 0.f;
    #pragma unroll 1
    for (int i = threadIdx.x; i < nblk; i += 256) {
        ls += partials[2 * i];
        ac += partials[2 * i + 1];
    }
    fb[threadIdx.x] = ls;
    fb[256 + threadIdx.x] = ac;
    __syncthreads();
    if (threadIdx.x == 0) {
        float L = 0.f, A = 0.f;
        for (int i = 0; i < 256; ++i) { L += fb[i]; A += fb[256 + i]; }
        out[0] = L * (1.0f / (float)BSZ);   // mean NLL (validated)
        out[1] = A;                          // accuracy count (validated)
    }
}

// ---------- fallback: validated fp32 path (r14) ----------
__global__ __launch_bounds__(256)
void cv20_fb_main(const float* __restrict__ img, const float* __restrict__ txt,
                  const float* __restrict__ w1, const float* __restrict__ b1,
                  const float* __restrict__ w2, const float* __restrict__ b2,
                  const unsigned* __restrict__ target, float* __restrict__ partials)
{
    __shared__ __align__(16) float arena[16000];
    __shared__ float red[256];
    __shared__ float smax[FBTM], sA[FBTM], srow[FBTM][2];
    __shared__ int   stgt[FBTM], sargmax[FBTM], tflag;

    const int t = threadIdx.x, blk = blockIdx.x, row0 = blk * FBTM;
    if (t == 0) {
        int allz = 1, small = 1;
        #pragma unroll 1
        for (int i = 0; i < 32; ++i) { allz &= (target[2*i+1]==0u); small &= (target[2*i]<1000000u); }
        tflag = (allz && small) ? 1 : 0;
    }
    __syncthreads();
    if (t < FBTM) {
        int r = row0 + t;
        int tg = (int)(tflag ? target[2*r] : target[r]);
        stgt[t] = tg < 0 ? 0 : (tg > NN-1 ? NN-1 : tg);
    }
    float* simg = arena; float* sh = arena + 8192;
    {
        const float4* src = (const float4*)(img + (size_t)row0 * DD);
        float4* dst = (float4*)simg;
        #pragma unroll
        for (int i = 0; i < 8; ++i) dst[t + i*256] = src[t + i*256];
    }
    __syncthreads();
    {
        const int c = t & 127, rh = t >> 7;
        float acc[8];
        #pragma unroll
        for (int i = 0; i < 8; ++i) acc[i] = 0.f;
        #pragma unroll 1
        for (int k = 0; k < DD; k += 4) {
            float w0=w1[(k+0)*HH+c], w1_=w1[(k+1)*HH+c], w2_=w1[(k+2)*HH+c], w3=w1[(k+3)*HH+c];
            #pragma unroll
            for (int i = 0; i < 8; ++i) {
                const float4 s = *(const float4*)&simg[(rh*8+i)*DD + k];
                acc[i] = fmaf(s.x,w0,fmaf(s.y,w1_,fmaf(s.z,w2_,fmaf(s.w,w3,acc[i]))));
            }
        }
        float bb = b1[c];
        #pragma unroll
        for (int i = 0; i < 8; ++i) sh[(rh*8+i)*HH + c] = fmaxf(acc[i]+bb, 0.f);
    }
    __syncthreads();
    {
        const int c0 = t, c1 = t + 256;
        float accA[FBTM], accB[FBTM];
        #pragma unroll
        for (int r = 0; r < FBTM; ++r) { accA[r]=0.f; accB[r]=0.f; }
        #pragma unroll 1
        for (int k = 0; k < HH; k += 4) {
            float wa[4], wb[4];
            #pragma unroll
            for (int u = 0; u < 4; ++u) { wa[u]=w2[(k+u)*DD+c0]; wb[u]=w2[(k+u)*DD+c1]; }
            #pragma unroll
            for (int r = 0; r < FBTM; ++r) {
                const float4 hv = *(const float4*)&sh[r*HH + k];
                accA[r]=fmaf(hv.x,wa[0],fmaf(hv.y,wa[1],fmaf(hv.z,wa[2],fmaf(hv.w,wa[3],accA[r]))));
                accB[r]=fmaf(hv.x,wb[0],fmaf(hv.y,wb[1],fmaf(hv.z,wb[2],fmaf(hv.w,wb[3],accB[r]))));
            }
        }
        const float ba = b2[c0], bb = b2[c1];
        #pragma unroll
        for (int r = 0; r < FBTM; ++r) {
            simg[r*DD+c0] = 0.5f*simg[r*DD+c0] + 0.5f*fmaxf(accA[r]+ba, 0.f);
            simg[r*DD+c1] = 0.5f*simg[r*DD+c1] + 0.5f*fmaxf(accB[r]+bb, 0.f);
        }
    }
    __syncthreads();
    float acc4[4][FBTM];
    #pragma unroll
    for (int c = 0; c < 4; ++c)
        #pragma unroll
        for (int r = 0; r < FBTM; ++r) acc4[c][r] = 0.f;
    const bool v3 = (768 + t) < NN;
    #pragma unroll 1
    for (int k = 0; k < DD; k += 4) {
        float tx[4][4];
        #pragma unroll
        for (int u = 0; u < 4; ++u) {
            const float* tp = txt + (size_t)(k+u)*NN;
            tx[0][u]=tp[t]; tx[1][u]=tp[256+t]; tx[2][u]=tp[512+t]; tx[3][u]=v3?tp[768+t]:0.f;
        }
        #pragma unroll
        for (int half = 0; half < 2; ++half) {
            float4 sv[8];
            #pragma unroll
            for (int i = 0; i < 8; ++i) sv[i] = *(const float4*)&simg[(half*8+i)*DD + k];
            #pragma unroll
            for (int i = 0; i < 8; ++i) {
                const int r = half*8 + i;
                #pragma unroll
                for (int c = 0; c < 4; ++c)
                    acc4[c][r]=fmaf(sv[i].x,tx[c][0],fmaf(sv[i].y,tx[c][1],fmaf(sv[i].z,tx[c][2],fmaf(sv[i].w,tx[c][3],acc4[c][r]))));
            }
        }
    }
    __syncthreads();
    #pragma unroll
    for (int c = 0; c < 4; ++c) {
        const int col = c*256 + t;
        if (col < NN)
            #pragma unroll
            for (int r = 0; r < FBTM; ++r) arena[r*NN + col] = acc4[c][r];
    }
    __syncthreads();
    const int myrow = t >> 4, ln = t & 15, tgt = stgt[myrow];
    {
        float S2 = 0.f;
        #pragma unroll 1
        for (int q = 0; q < 63; ++q) { int j = ln + (q<<4); if (j < NN) { float v = arena[myrow*NN+j]; S2 += v*v; } }
        red[t] = S2; __syncthreads();
        if (ln == 0) { float s=0.f; for (int i=0;i<16;++i) s+=red[myrow*16+i]; sA[myrow]=1.0f/sqrtf(s); }
        __syncthreads();
    }
    const float a = sA[myrow];
    #pragma unroll 1
    for (int q = 0; q < 63; ++q) { int j = ln + (q<<4); if (j < NN) arena[myrow*NN+j] *= a; }
    __syncthreads();
    if (t < FBTM) {
        const float* rp = &arena[t*NN];
        float bm = rp[0]; int bi = 0;
        #pragma unroll 4
        for (int j = 1; j < NN; ++j) { float v = rp[j]; if (v > bm) { bm = v; bi = j; } }
        sargmax[t] = bi;
    }
    __syncthreads();
    float mx = -1e30f, vtl = -1e30f;
    #pragma unroll 1
    for (int q = 0; q < 63; ++q) {
        int j = ln + (q<<4);
        if (j < NN) { float v = arena[myrow*NN+j]; mx = fmaxf(mx, v); if (j == tgt) vtl = v; }
    }
    red[t] = mx; __syncthreads();
    float rowmax = -1e30f;
    if (ln == 0) { for (int i=0;i<16;++i) rowmax = fmaxf(rowmax, red[myrow*16+i]); smax[myrow] = rowmax; }
    __syncthreads();
    rowmax = smax[myrow];
    red[t] = vtl; __syncthreads();
    float vt = -1e30f;
    if (ln == 0) { for (int i=0;i<16;++i) vt = fmaxf(vt, red[myrow*16+i]); }
    __syncthreads();
    float E = 0.f;
    #pragma unroll 1
    for (int q = 0; q < 63; ++q) { int j = ln + (q<<4); if (j < NN) E += expf(arena[myrow*NN+j] - rowmax); }
    red[t] = E; __syncthreads();
    if (ln == 0) {
        float Er = 0.f; for (int i=0;i<16;++i) Er += red[myrow*16+i];
        srow[myrow][0] = (rowmax - vt) + logf(Er);
        srow[myrow][1] = (sargmax[myrow] == tgt) ? 1.f : 0.f;
    }
    __syncthreads();
    if (t == 0) {
        float ls = 0.f, ac = 0.f;
        #pragma unroll
        for (int r = 0; r < FBTM; ++r) { ls += srow[r][0]; ac += srow[r][1]; }
        partials[blk*2+0] = ls; partials[blk*2+1] = ac;
    }
}

extern "C" void kernel_launch(void* const* d_in, const int* in_sizes, int n_in,
                              void* d_out, int out_size, void* d_ws, size_t ws_size,
                              hipStream_t stream)
{
    const void *img = nullptr, *txt = nullptr, *w1 = nullptr, *w2 = nullptr;
    const void *b1 = nullptr, *b2 = nullptr, *tgt = nullptr;
    for (int i = 0; i < n_in; ++i) {
        long s = in_sizes[i];
        if      (s == (long)BSZ * DD) img = d_in[i];
        else if (s == (long)DD * NN)  txt = d_in[i];
        else if (s == (long)DD * HH) { if (!w1) w1 = d_in[i]; else w2 = d_in[i]; }
        else if (s == HH)  b1 = d_in[i];
        else if (s == DD)  b2 = d_in[i];
        else if (s == BSZ) tgt = d_in[i];
    }
    if (!img || !txt || !w1 || !w2 || !b1 || !b2 || !tgt) {
        img = d_in[0]; txt = d_in[1]; w1 = d_in[2]; b1 = d_in[3];
        w2 = d_in[4]; b2 = d_in[5]; tgt = d_in[8];
    }

    const size_t nTxt = (size_t)1024 * 512, nW = (size_t)128 * 512;
    const size_t needBytes = (2 * nTxt + 4 * nW) * 2 + 16384 + 256;

    if (ws_size >= needBytes) {
        unsigned short* txtTh = (unsigned short*)d_ws;
        unsigned short* txtTl = txtTh + nTxt;
        unsigned short* w1Th  = txtTl + nTxt;
        unsigned short* w1Tl  = w1Th + nW;
        unsigned short* w2Th  = w1Tl + nW;
        unsigned short* w2Tl  = w2Th + nW;
        float* partials = (float*)(w2Tl + nW);

        cv20_prep_txt<<<1024, 256, 0, stream>>>((const float*)txt, txtTh, txtTl);
        cv20_prep_w1<<<128, 256, 0, stream>>>((const float*)w1, w1Th, w1Tl);
        cv20_prep_w2<<<512, 128, 0, stream>>>((const float*)w2, w2Th, w2Tl);
        cv20_main<<<NBLK, 1024, 0, stream>>>((const float*)img, (const float*)b1,
                                             (const float*)b2, txtTh, txtTl,
                                             w1Th, w1Tl, w2Th, w2Tl,
                                             (const unsigned*)tgt, partials);
        cv20_final<<<1, 256, 0, stream>>>(partials, NBLK, (float*)d_out);
    } else {
        float* partials = (float*)d_ws;
        cv20_fb_main<<<FBBLK, 256, 0, stream>>>((const float*)img, (const float*)txt,
                                                (const float*)w1, (const float*)b1,
                                                (const float*)w2, (const float*)b2,
                                                (const unsigned*)tgt, partials);
        cv20_final<<<1, 256, 0, stream>>>(partials, FBBLK, (float*)d_out);
    }
}

// Round 21
// 383.093 us; speedup vs baseline: 1.6569x; 1.6569x over previous
//
#include <hip/hip_runtime.h>
#include <math.h>

#define BSZ   32768
#define DD    512
#define HH    128
#define NN    1000
#define TM    32
#define NBLK  (BSZ / TM)   // 1024
#define FBTM  16
#define FBBLK (BSZ / FBTM) // 2048

typedef short  bf8 __attribute__((ext_vector_type(8)));
typedef float  f4  __attribute__((ext_vector_type(4)));

__device__ __forceinline__ unsigned short cv21_f2bf(float f) {
    unsigned u = __float_as_uint(f);
    u = u + 0x7FFF + ((u >> 16) & 1);
    return (unsigned short)(u >> 16);
}
__device__ __forceinline__ float cv21_bf2f(unsigned short h) {
    return __uint_as_float(((unsigned)h) << 16);
}

#define MFMA16(a, b, c) __builtin_amdgcn_mfma_f32_16x16x32_bf16((a), (b), (c), 0, 0, 0)

// ---------- pre-kernels (validated r15-r20) ----------
__global__ void cv21_prep_txt(const float* __restrict__ txt,
                              unsigned short* __restrict__ th,
                              unsigned short* __restrict__ tl)
{
    int j = blockIdx.x;                       // 0..1023, zero-padded
    for (int k = threadIdx.x; k < DD; k += blockDim.x) {
        float v = (j < NN) ? txt[(size_t)k * NN + j] : 0.f;
        unsigned short h = cv21_f2bf(v);
        unsigned short l = cv21_f2bf(v - cv21_bf2f(h));
        th[(size_t)j * DD + k] = h;
        tl[(size_t)j * DD + k] = l;
    }
}
__global__ void cv21_prep_w1(const float* __restrict__ w1,
                             unsigned short* __restrict__ th,
                             unsigned short* __restrict__ tl)
{
    int j = blockIdx.x;                       // 0..127
    for (int k = threadIdx.x; k < DD; k += blockDim.x) {
        float v = w1[(size_t)k * HH + j];
        unsigned short h = cv21_f2bf(v);
        unsigned short l = cv21_f2bf(v - cv21_bf2f(h));
        th[(size_t)j * DD + k] = h;
        tl[(size_t)j * DD + k] = l;
    }
}
__global__ void cv21_prep_w2(const float* __restrict__ w2,
                             unsigned short* __restrict__ th,
                             unsigned short* __restrict__ tl)
{
    int j = blockIdx.x;                       // 0..511
    for (int k = threadIdx.x; k < HH; k += blockDim.x) {
        float v = w2[(size_t)k * DD + j];
        unsigned short h = cv21_f2bf(v);
        unsigned short l = cv21_f2bf(v - cv21_bf2f(h));
        th[(size_t)j * HH + k] = h;
        tl[(size_t)j * HH + k] = l;
    }
}

// ---------- main: TM=32, 16 waves; P4 = LDS-staged B panel, coalesced loads ----------
__global__ __launch_bounds__(1024, 4)
void cv21_main(const float* __restrict__ img,
               const float* __restrict__ b1,
               const float* __restrict__ b2,
               const unsigned short* __restrict__ txtTh,
               const unsigned short* __restrict__ txtTl,
               const unsigned short* __restrict__ w1Th,
               const unsigned short* __restrict__ w1Tl,
               const unsigned short* __restrict__ w2Th,
               const unsigned short* __restrict__ w2Tl,
               const unsigned* __restrict__ target,
               float* __restrict__ partials)
{
    __shared__ unsigned short YH[2][8192];   // 32 KB A-frag hi per row-group
    __shared__ unsigned short YL[2][8192];   // 32 KB A-frag lo
    __shared__ unsigned short BH[18432];     // 36.9 KB: 256 runs x 72 (64+8 pad) shorts
    __shared__ unsigned short BL[18432];     // 36.9 KB
    __shared__ float red[1024];
    __shared__ float sAr[TM], sMx[TM], sVt[TM];
    __shared__ float srow[TM][2];
    __shared__ int   stgt[TM];
    __shared__ int   tflag;

    unsigned short* hfH = &YH[0][0];       // alias; barriers separate lifetimes
    unsigned short* hfL = &YH[0][4096];

    const int t    = threadIdx.x;
    const int w    = t >> 6;        // wave 0..15
    const int l    = t & 63;
    const int wr   = w >> 3;        // row-group 0/1
    const int wc   = w & 7;         // col-group 0..7
    const int blk  = blockIdx.x;
    const int row0 = blk * TM;

    if (t == 0) {
        int allz = 1, small = 1;
        #pragma unroll 1
        for (int i = 0; i < 32; ++i) {
            allz  &= (target[2 * i + 1] == 0u);
            small &= (target[2 * i] < 1000000u);
        }
        tflag = (allz && small) ? 1 : 0;
    }
    __syncthreads();
    if (t < TM) {
        int r = row0 + t;
        int tg = (int)(tflag ? target[2 * r] : target[r]);
        if (tg < 0) tg = 0;
        if (tg > NN - 1) tg = NN - 1;
        stgt[t] = tg;
    }

    // P1: pack img A-fragments from global (2 k-tiles per wave) [r17/r20-validated]
    #pragma unroll
    for (int s = 0; s < 2; ++s) {
        const int kt = wc * 2 + s;
        const float* ip = img + (size_t)(row0 + wr * 16 + (l & 15)) * DD + kt * 32 + (l >> 4) * 8;
        float4 v0 = *(const float4*)ip;
        float4 v1 = *(const float4*)(ip + 4);
        float xs[8] = {v0.x, v0.y, v0.z, v0.w, v1.x, v1.y, v1.z, v1.w};
        bf8 vh, vl;
        #pragma unroll
        for (int e = 0; e < 8; ++e) {
            unsigned short hh = cv21_f2bf(xs[e]);
            vh[e] = (short)hh;
            vl[e] = (short)cv21_f2bf(xs[e] - cv21_bf2f(hh));
        }
        *(bf8*)&YH[wr][kt * 512 + l * 8] = vh;
        *(bf8*)&YL[wr][kt * 512 + l * 8] = vl;
    }
    __syncthreads();

    // P2: h = relu(img @ w1 + b1) [validated]
    float hv[4];
    {
        f4 acc = {0.f, 0.f, 0.f, 0.f};
        const int jj = wc * 16 + (l & 15);
        const unsigned short* bh = w1Th + (size_t)jj * DD + ((l >> 4) * 8);
        const unsigned short* bl = w1Tl + (size_t)jj * DD + ((l >> 4) * 8);
        #pragma unroll 4
        for (int kt = 0; kt < 16; ++kt) {
            bf8 ah = *(const bf8*)&YH[wr][kt * 512 + l * 8];
            bf8 al = *(const bf8*)&YL[wr][kt * 512 + l * 8];
            bf8 wh = *(const bf8*)(bh + kt * 32);
            bf8 wl = *(const bf8*)(bl + kt * 32);
            acc = MFMA16(ah, wh, acc);
            acc = MFMA16(ah, wl, acc);
            acc = MFMA16(al, wh, acc);
        }
        float bv = b1[jj];
        #pragma unroll
        for (int r = 0; r < 4; ++r) hv[r] = fmaxf(acc[r] + bv, 0.f);
    }
    __syncthreads();

    // P2b: scatter h into hf fragment layout [validated]
    {
        const int jj  = wc * 16 + (l & 15);
        const int kt2 = jj >> 5;
        const int e   = jj & 7;
        const int hi4 = ((jj >> 3) & 3) << 4;
        #pragma unroll
        for (int r = 0; r < 4; ++r) {
            int row16 = (l >> 4) * 4 + r;
            int lane2 = row16 | hi4;
            unsigned short hh = cv21_f2bf(hv[r]);
            hfH[wr * 2048 + kt2 * 512 + lane2 * 8 + e] = hh;
            hfL[wr * 2048 + kt2 * 512 + lane2 * 8 + e] = cv21_f2bf(hv[r] - cv21_bf2f(hh));
        }
    }
    __syncthreads();

    // P3: adapted = relu(h @ w2 + b2); blend with img re-read [validated]
    float blv[4][4];
    {
        const int c15 = l & 15;
        #pragma unroll
        for (int ti = 0; ti < 4; ++ti) {
            const int tix = wc + ti * 8;
            const int jj  = tix * 16 + c15;
            f4 acc = {0.f, 0.f, 0.f, 0.f};
            const unsigned short* bh = w2Th + (size_t)jj * HH + ((l >> 4) * 8);
            const unsigned short* bl = w2Tl + (size_t)jj * HH + ((l >> 4) * 8);
            #pragma unroll
            for (int kt = 0; kt < 4; ++kt) {
                bf8 ah = *(const bf8*)&hfH[wr * 2048 + kt * 512 + l * 8];
                bf8 al = *(const bf8*)&hfL[wr * 2048 + kt * 512 + l * 8];
                bf8 wh = *(const bf8*)(bh + kt * 32);
                bf8 wl = *(const bf8*)(bl + kt * 32);
                acc = MFMA16(ah, wh, acc);
                acc = MFMA16(ah, wl, acc);
                acc = MFMA16(al, wh, acc);
            }
            float bv = b2[jj];
            #pragma unroll
            for (int r = 0; r < 4; ++r) {
                int row16 = (l >> 4) * 4 + r;
                float iv = img[(size_t)(row0 + wr * 16 + row16) * DD + jj];
                blv[ti][r] = 0.5f * iv + 0.5f * fmaxf(acc[r] + bv, 0.f);
            }
        }
    }
    __syncthreads();

    // P3b: scatter img_adapted into YH/YL [validated]
    {
        const int c15 = l & 15;
        #pragma unroll
        for (int ti = 0; ti < 4; ++ti) {
            const int tix = wc + ti * 8;
            const int jj  = tix * 16 + c15;
            const int kt  = jj >> 5;
            const int e   = jj & 7;
            const int hi4 = ((jj >> 3) & 3) << 4;
            #pragma unroll
            for (int r = 0; r < 4; ++r) {
                int row16 = (l >> 4) * 4 + r;
                int lane2 = row16 | hi4;
                unsigned short hh = cv21_f2bf(blv[ti][r]);
                YH[wr][kt * 512 + lane2 * 8 + e] = hh;
                YL[wr][kt * 512 + lane2 * 8 + e] = cv21_f2bf(blv[ti][r] - cv21_bf2f(hh));
            }
        }
    }
    __syncthreads();

    // P4: sim via LDS-staged B panel. 4 passes x 8 k-chunks (64 k each).
    // Acc mapping identical to r20: simacc[p*2+c] <-> tile = p*16 + wc + c*8.
    f4 simacc[8];
    #pragma unroll
    for (int i = 0; i < 8; ++i) simacc[i] = (f4){0.f, 0.f, 0.f, 0.f};

    const int runT = t >> 2;        // 0..255 staging run (global col p*256+runT)
    const int part = t & 3;         // 0..3 (32B each of the 128B run-chunk)
    const int c15  = l & 15;
    const int kof  = (l >> 4) * 8;

    #pragma unroll
    for (int p = 0; p < 4; ++p) {
        #pragma unroll 1
        for (int ktc = 0; ktc < 8; ++ktc) {
            __syncthreads();   // previous chunk's LDS reads complete
            {   // stage B-slice: cols p*256..p*256+255, k ktc*64..+63 (contiguous loads)
                const size_t g = (size_t)(p * 256 + runT) * DD + ktc * 64 + part * 16;
                bf8 h0 = *(const bf8*)(txtTh + g);
                bf8 h1 = *(const bf8*)(txtTh + g + 8);
                bf8 l0 = *(const bf8*)(txtTl + g);
                bf8 l1 = *(const bf8*)(txtTl + g + 8);
                unsigned short* dh = &BH[runT * 72 + part * 16];
                *(bf8*)dh = h0; *(bf8*)(dh + 8) = h1;
                unsigned short* dl = &BL[runT * 72 + part * 16];
                *(bf8*)dl = l0; *(bf8*)(dl + 8) = l1;
            }
            __syncthreads();   // staged data visible
            #pragma unroll
            for (int ktl = 0; ktl < 2; ++ktl) {
                const int kt = ktc * 2 + ktl;   // global k-tile 0..15
                bf8 ah = *(const bf8*)&YH[wr][kt * 512 + l * 8];
                bf8 al = *(const bf8*)&YL[wr][kt * 512 + l * 8];
                const int runA = wc * 16 + c15;          // local tile wc
                const int runB = (wc + 8) * 16 + c15;    // local tile wc+8
                bf8 bAh = *(const bf8*)&BH[runA * 72 + ktl * 32 + kof];
                bf8 bAl = *(const bf8*)&BL[runA * 72 + ktl * 32 + kof];
                bf8 bBh = *(const bf8*)&BH[runB * 72 + ktl * 32 + kof];
                bf8 bBl = *(const bf8*)&BL[runB * 72 + ktl * 32 + kof];
                simacc[p * 2]     = MFMA16(ah, bAh, simacc[p * 2]);
                simacc[p * 2 + 1] = MFMA16(ah, bBh, simacc[p * 2 + 1]);
                simacc[p * 2]     = MFMA16(ah, bAl, simacc[p * 2]);
                simacc[p * 2 + 1] = MFMA16(ah, bBl, simacc[p * 2 + 1]);
                simacc[p * 2]     = MFMA16(al, bAh, simacc[p * 2]);
                simacc[p * 2 + 1] = MFMA16(al, bBh, simacc[p * 2 + 1]);
            }
        }
    }
    __syncthreads();

    // ---- epilogue from registers [r20-validated; same tix formula] ----
    float s2v[4] = {0.f, 0.f, 0.f, 0.f};
    float mxv[4] = {-1e30f, -1e30f, -1e30f, -1e30f};
    float vtv[4] = {-1e30f, -1e30f, -1e30f, -1e30f};
    int   mxi[4] = {0x7fffffff, 0x7fffffff, 0x7fffffff, 0x7fffffff};

    #pragma unroll
    for (int i = 0; i < 8; ++i) {
        const int tix = wc + (i >> 1) * 16 + (i & 1) * 8;
        const int col = tix * 16 + (l & 15);
        const bool ok = col < NN;
        #pragma unroll
        for (int r = 0; r < 4; ++r) {
            float v = simacc[i][r];
            if (ok) {
                s2v[r] += v * v;
                if (v > mxv[r] || (v == mxv[r] && col < mxi[r])) { mxv[r] = v; mxi[r] = col; }
                int R = wr * 16 + (l >> 4) * 4 + r;
                if (col == stgt[R]) vtv[r] = v;
            }
        }
    }
    #pragma unroll
    for (int m = 1; m < 16; m <<= 1) {
        #pragma unroll
        for (int r = 0; r < 4; ++r) {
            s2v[r] += __shfl_xor(s2v[r], m);
            float ov = __shfl_xor(mxv[r], m);
            int   oi = __shfl_xor(mxi[r], m);
            if (ov > mxv[r] || (ov == mxv[r] && oi < mxi[r])) { mxv[r] = ov; mxi[r] = oi; }
            vtv[r] = fmaxf(vtv[r], __shfl_xor(vtv[r], m));
        }
    }
    if ((l & 15) == 0) {
        #pragma unroll
        for (int r = 0; r < 4; ++r) {
            int R = wr * 16 + (l >> 4) * 4 + r;
            red[  0 + R * 8 + wc] = s2v[r];
            red[256 + R * 8 + wc] = mxv[r];
            red[512 + R * 8 + wc] = __int_as_float(mxi[r]);
            red[768 + R * 8 + wc] = vtv[r];
        }
    }
    __syncthreads();
    if (t < TM) {
        float S2 = 0.f, MX = -1e30f, VT = -1e30f;
        int MI = 0x7fffffff;
        #pragma unroll
        for (int ww = 0; ww < 8; ++ww) {
            S2 += red[t * 8 + ww];
            float ov = red[256 + t * 8 + ww];
            int   oi = __float_as_int(red[512 + t * 8 + ww]);
            if (ov > MX || (ov == MX && oi < MI)) { MX = ov; MI = oi; }
            VT = fmaxf(VT, red[768 + t * 8 + ww]);
        }
        sAr[t] = 1.0f / sqrtf(S2);
        sMx[t] = MX;
        sVt[t] = VT;
        srow[t][1] = (MI == stgt[t]) ? 1.f : 0.f;
    }
    __syncthreads();

    float es[4] = {0.f, 0.f, 0.f, 0.f};
    #pragma unroll
    for (int i = 0; i < 8; ++i) {
        const int tix = wc + (i >> 1) * 16 + (i & 1) * 8;
        const int col = tix * 16 + (l & 15);
        const bool ok = col < NN;
        #pragma unroll
        for (int r = 0; r < 4; ++r) {
            if (ok) {
                int R = wr * 16 + (l >> 4) * 4 + r;
                es[r] += expf((simacc[i][r] - sMx[R]) * sAr[R]);
            }
        }
    }
    #pragma unroll
    for (int m = 1; m < 16; m <<= 1) {
        #pragma unroll
        for (int r = 0; r < 4; ++r) es[r] += __shfl_xor(es[r], m);
    }
    if ((l & 15) == 0) {
        #pragma unroll
        for (int r = 0; r < 4; ++r) {
            int R = wr * 16 + (l >> 4) * 4 + r;
            red[R * 8 + wc] = es[r];
        }
    }
    __syncthreads();
    if (t < TM) {
        float E = 0.f;
        #pragma unroll
        for (int ww = 0; ww < 8; ++ww) E += red[t * 8 + ww];
        srow[t][0] = (sMx[t] - sVt[t]) * sAr[t] + logf(E);
    }
    __syncthreads();
    if (t == 0) {
        float ls = 0.f, ac = 0.f;
        #pragma unroll
        for (int r = 0; r < TM; ++r) { ls += srow[r][0]; ac += srow[r][1]; }
        partials[blk * 2 + 0] = ls;
        partials[blk * 2 + 1] = ac;
    }
}

__global__ __launch_bounds__(256)
void cv21_final(const float* __restrict__ partials, int nblk, float* __restrict__ out)
{
    __shared__ float fb[512];
    float ls = 0.f, ac = 0.f;
    #pragma unroll 1
    for (int i = threadIdx.x; i < nblk; i += 256) {
        ls += partials[2 * i];
        ac += partials[2 * i + 1];
    }
    fb[threadIdx.x] = ls;
    fb[256 + threadIdx.x] = ac;
    __syncthreads();
    if (threadIdx.x == 0) {
        float L = 0.f, A = 0.f;
        for (int i = 0; i < 256; ++i) { L += fb[i]; A += fb[256 + i]; }
        out[0] = L * (1.0f / (float)BSZ);   // mean NLL (validated)
        out[1] = A;                          // accuracy count (validated)
    }
}

// ---------- fallback: validated fp32 path (r14) ----------
__global__ __launch_bounds__(256)
void cv21_fb_main(const float* __restrict__ img, const float* __restrict__ txt,
                  const float* __restrict__ w1, const float* __restrict__ b1,
                  const float* __restrict__ w2, const float* __restrict__ b2,
                  const unsigned* __restrict__ target, float* __restrict__ partials)
{
    __shared__ __align__(16) float arena[16000];
    __shared__ float red[256];
    __shared__ float smax[FBTM], sA[FBTM], srow[FBTM][2];
    __shared__ int   stgt[FBTM], sargmax[FBTM], tflag;

    const int t = threadIdx.x, blk = blockIdx.x, row0 = blk * FBTM;
    if (t == 0) {
        int allz = 1, small = 1;
        #pragma unroll 1
        for (int i = 0; i < 32; ++i) { allz &= (target[2*i+1]==0u); small &= (target[2*i]<1000000u); }
        tflag = (allz && small) ? 1 : 0;
    }
    __syncthreads();
    if (t < FBTM) {
        int r = row0 + t;
        int tg = (int)(tflag ? target[2*r] : target[r]);
        stgt[t] = tg < 0 ? 0 : (tg > NN-1 ? NN-1 : tg);
    }
    float* simg = arena; float* sh = arena + 8192;
    {
        const float4* src = (const float4*)(img + (size_t)row0 * DD);
        float4* dst = (float4*)simg;
        #pragma unroll
        for (int i = 0; i < 8; ++i) dst[t + i*256] = src[t + i*256];
    }
    __syncthreads();
    {
        const int c = t & 127, rh = t >> 7;
        float acc[8];
        #pragma unroll
        for (int i = 0; i < 8; ++i) acc[i] = 0.f;
        #pragma unroll 1
        for (int k = 0; k < DD; k += 4) {
            float w0=w1[(k+0)*HH+c], w1_=w1[(k+1)*HH+c], w2_=w1[(k+2)*HH+c], w3=w1[(k+3)*HH+c];
            #pragma unroll
            for (int i = 0; i < 8; ++i) {
                const float4 s = *(const float4*)&simg[(rh*8+i)*DD + k];
                acc[i] = fmaf(s.x,w0,fmaf(s.y,w1_,fmaf(s.z,w2_,fmaf(s.w,w3,acc[i]))));
            }
        }
        float bb = b1[c];
        #pragma unroll
        for (int i = 0; i < 8; ++i) sh[(rh*8+i)*HH + c] = fmaxf(acc[i]+bb, 0.f);
    }
    __syncthreads();
    {
        const int c0 = t, c1 = t + 256;
        float accA[FBTM], accB[FBTM];
        #pragma unroll
        for (int r = 0; r < FBTM; ++r) { accA[r]=0.f; accB[r]=0.f; }
        #pragma unroll 1
        for (int k = 0; k < HH; k += 4) {
            float wa[4], wb[4];
            #pragma unroll
            for (int u = 0; u < 4; ++u) { wa[u]=w2[(k+u)*DD+c0]; wb[u]=w2[(k+u)*DD+c1]; }
            #pragma unroll
            for (int r = 0; r < FBTM; ++r) {
                const float4 hv = *(const float4*)&sh[r*HH + k];
                accA[r]=fmaf(hv.x,wa[0],fmaf(hv.y,wa[1],fmaf(hv.z,wa[2],fmaf(hv.w,wa[3],accA[r]))));
                accB[r]=fmaf(hv.x,wb[0],fmaf(hv.y,wb[1],fmaf(hv.z,wb[2],fmaf(hv.w,wb[3],accB[r]))));
            }
        }
        const float ba = b2[c0], bb = b2[c1];
        #pragma unroll
        for (int r = 0; r < FBTM; ++r) {
            simg[r*DD+c0] = 0.5f*simg[r*DD+c0] + 0.5f*fmaxf(accA[r]+ba, 0.f);
            simg[r*DD+c1] = 0.5f*simg[r*DD+c1] + 0.5f*fmaxf(accB[r]+bb, 0.f);
        }
    }
    __syncthreads();
    float acc4[4][FBTM];
    #pragma unroll
    for (int c = 0; c < 4; ++c)
        #pragma unroll
        for (int r = 0; r < FBTM; ++r) acc4[c][r] = 0.f;
    const bool v3 = (768 + t) < NN;
    #pragma unroll 1
    for (int k = 0; k < DD; k += 4) {
        float tx[4][4];
        #pragma unroll
        for (int u = 0; u < 4; ++u) {
            const float* tp = txt + (size_t)(k+u)*NN;
            tx[0][u]=tp[t]; tx[1][u]=tp[256+t]; tx[2][u]=tp[512+t]; tx[3][u]=v3?tp[768+t]:0.f;
        }
        #pragma unroll
        for (int half = 0; half < 2; ++half) {
            float4 sv[8];
            #pragma unroll
            for (int i = 0; i < 8; ++i) sv[i] = *(const float4*)&simg[(half*8+i)*DD + k];
            #pragma unroll
            for (int i = 0; i < 8; ++i) {
                const int r = half*8 + i;
                #pragma unroll
                for (int c = 0; c < 4; ++c)
                    acc4[c][r]=fmaf(sv[i].x,tx[c][0],fmaf(sv[i].y,tx[c][1],fmaf(sv[i].z,tx[c][2],fmaf(sv[i].w,tx[c][3],acc4[c][r]))));
            }
        }
    }
    __syncthreads();
    #pragma unroll
    for (int c = 0; c < 4; ++c) {
        const int col = c*256 + t;
        if (col < NN)
            #pragma unroll
            for (int r = 0; r < FBTM; ++r) arena[r*NN + col] = acc4[c][r];
    }
    __syncthreads();
    const int myrow = t >> 4, ln = t & 15, tgt = stgt[myrow];
    {
        float S2 = 0.f;
        #pragma unroll 1
        for (int q = 0; q < 63; ++q) { int j = ln + (q<<4); if (j < NN) { float v = arena[myrow*NN+j]; S2 += v*v; } }
        red[t] = S2; __syncthreads();
        if (ln == 0) { float s=0.f; for (int i=0;i<16;++i) s+=red[myrow*16+i]; sA[myrow]=1.0f/sqrtf(s); }
        __syncthreads();
    }
    const float a = sA[myrow];
    #pragma unroll 1
    for (int q = 0; q < 63; ++q) { int j = ln + (q<<4); if (j < NN) arena[myrow*NN+j] *= a; }
    __syncthreads();
    if (t < FBTM) {
        const float* rp = &arena[t*NN];
        float bm = rp[0]; int bi = 0;
        #pragma unroll 4
        for (int j = 1; j < NN; ++j) { float v = rp[j]; if (v > bm) { bm = v; bi = j; } }
        sargmax[t] = bi;
    }
    __syncthreads();
    float mx = -1e30f, vtl = -1e30f;
    #pragma unroll 1
    for (int q = 0; q < 63; ++q) {
        int j = ln + (q<<4);
        if (j < NN) { float v = arena[myrow*NN+j]; mx = fmaxf(mx, v); if (j == tgt) vtl = v; }
    }
    red[t] = mx; __syncthreads();
    float rowmax = -1e30f;
    if (ln == 0) { for (int i=0;i<16;++i) rowmax = fmaxf(rowmax, red[myrow*16+i]); smax[myrow] = rowmax; }
    __syncthreads();
    rowmax = smax[myrow];
    red[t] = vtl; __syncthreads();
    float vt = -1e30f;
    if (ln == 0) { for (int i=0;i<16;++i) vt = fmaxf(vt, red[myrow*16+i]); }
    __syncthreads();
    float E = 0.f;
    #pragma unroll 1
    for (int q = 0; q < 63; ++q) { int j = ln + (q<<4); if (j < NN) E += expf(arena[myrow*NN+j] - rowmax); }
    red[t] = E; __syncthreads();
    if (ln == 0) {
        float Er = 0.f; for (int i=0;i<16;++i) Er += red[myrow*16+i];
        srow[myrow][0] = (rowmax - vt) + logf(Er);
        srow[myrow][1] = (sargmax[myrow] == tgt) ? 1.f : 0.f;
    }
    __syncthreads();
    if (t == 0) {
        float ls = 0.f, ac = 0.f;
        #pragma unroll
        for (int r = 0; r < FBTM; ++r) { ls += srow[r][0]; ac += srow[r][1]; }
        partials[blk*2+0] = ls; partials[blk*2+1] = ac;
    }
}

extern "C" void kernel_launch(void* const* d_in, const int* in_sizes, int n_in,
                              void* d_out, int out_size, void* d_ws, size_t ws_size,
                              hipStream_t stream)
{
    const void *img = nullptr, *txt = nullptr, *w1 = nullptr, *w2 = nullptr;
    const void *b1 = nullptr, *b2 = nullptr, *tgt = nullptr;
    for (int i = 0; i < n_in; ++i) {
        long s = in_sizes[i];
        if      (s == (long)BSZ * DD) img = d_in[i];
        else if (s == (long)DD * NN)  txt = d_in[i];
        else if (s == (long)DD * HH) { if (!w1) w1 = d_in[i]; else w2 = d_in[i]; }
        else if (s == HH)  b1 = d_in[i];
        else if (s == DD)  b2 = d_in[i];
        else if (s == BSZ) tgt = d_in[i];
    }
    if (!img || !txt || !w1 || !w2 || !b1 || !b2 || !tgt) {
        img = d_in[0]; txt = d_in[1]; w1 = d_in[2]; b1 = d_in[3];
        w2 = d_in[4]; b2 = d_in[5]; tgt = d_in[8];
    }

    const size_t nTxt = (size_t)1024 * 512, nW = (size_t)128 * 512;
    const size_t needBytes = (2 * nTxt + 4 * nW) * 2 + 16384 + 256;

    if (ws_size >= needBytes) {
        unsigned short* txtTh = (unsigned short*)d_ws;
        unsigned short* txtTl = txtTh + nTxt;
        unsigned short* w1Th  = txtTl + nTxt;
        unsigned short* w1Tl  = w1Th + nW;
        unsigned short* w2Th  = w1Tl + nW;
        unsigned short* w2Tl  = w2Th + nW;
        float* partials = (float*)(w2Tl + nW);

        cv21_prep_txt<<<1024, 256, 0, stream>>>((const float*)txt, txtTh, txtTl);
        cv21_prep_w1<<<128, 256, 0, stream>>>((const float*)w1, w1Th, w1Tl);
        cv21_prep_w2<<<512, 128, 0, stream>>>((const float*)w2, w2Th, w2Tl);
        cv21_main<<<NBLK, 1024, 0, stream>>>((const float*)img, (const float*)b1,
                                             (const float*)b2, txtTh, txtTl,
                                             w1Th, w1Tl, w2Th, w2Tl,
                                             (const unsigned*)tgt, partials);
        cv21_final<<<1, 256, 0, stream>>>(partials, NBLK, (float*)d_out);
    } else {
        float* partials = (float*)d_ws;
        cv21_fb_main<<<FBBLK, 256, 0, stream>>>((const float*)img, (const float*)txt,
                                                (const float*)w1, (const float*)b1,
                                                (const float*)w2, (const float*)b2,
                                                (const unsigned*)tgt, partials);
        cv21_final<<<1, 256, 0, stream>>>(partials, FBBLK, (float*)d_out);
    }
}

// Round 22
// 340.792 us; speedup vs baseline: 1.8626x; 1.1241x over previous
//
#include <hip/hip_runtime.h>
#include <math.h>

#define BSZ   32768
#define DD    512
#define HH    128
#define NN    1000
#define TM    32
#define NBLK  (BSZ / TM)   // 1024
#define FBTM  16
#define FBBLK (BSZ / FBTM) // 2048

typedef short  bf8 __attribute__((ext_vector_type(8)));
typedef float  f4  __attribute__((ext_vector_type(4)));

__device__ __forceinline__ unsigned short cv22_f2bf(float f) {
    unsigned u = __float_as_uint(f);
    u = u + 0x7FFF + ((u >> 16) & 1);
    return (unsigned short)(u >> 16);
}
__device__ __forceinline__ float cv22_bf2f(unsigned short h) {
    return __uint_as_float(((unsigned)h) << 16);
}

#define MFMA16(a, b, c) __builtin_amdgcn_mfma_f32_16x16x32_bf16((a), (b), (c), 0, 0, 0)

// ---------- pre-kernels (validated r15-r21) ----------
__global__ void cv22_prep_txt(const float* __restrict__ txt,
                              unsigned short* __restrict__ th,
                              unsigned short* __restrict__ tl)
{
    int j = blockIdx.x;                       // 0..1023, zero-padded
    for (int k = threadIdx.x; k < DD; k += blockDim.x) {
        float v = (j < NN) ? txt[(size_t)k * NN + j] : 0.f;
        unsigned short h = cv22_f2bf(v);
        unsigned short l = cv22_f2bf(v - cv22_bf2f(h));
        th[(size_t)j * DD + k] = h;
        tl[(size_t)j * DD + k] = l;
    }
}
__global__ void cv22_prep_w1(const float* __restrict__ w1,
                             unsigned short* __restrict__ th,
                             unsigned short* __restrict__ tl)
{
    int j = blockIdx.x;                       // 0..127
    for (int k = threadIdx.x; k < DD; k += blockDim.x) {
        float v = w1[(size_t)k * HH + j];
        unsigned short h = cv22_f2bf(v);
        unsigned short l = cv22_f2bf(v - cv22_bf2f(h));
        th[(size_t)j * DD + k] = h;
        tl[(size_t)j * DD + k] = l;
    }
}
__global__ void cv22_prep_w2(const float* __restrict__ w2,
                             unsigned short* __restrict__ th,
                             unsigned short* __restrict__ tl)
{
    int j = blockIdx.x;                       // 0..511
    for (int k = threadIdx.x; k < HH; k += blockDim.x) {
        float v = w2[(size_t)k * DD + j];
        unsigned short h = cv22_f2bf(v);
        unsigned short l = cv22_f2bf(v - cv22_bf2f(h));
        th[(size_t)j * HH + k] = h;
        tl[(size_t)j * HH + k] = l;
    }
}

// ---------- main: TM=32, 16 waves; P4 = LDS-staged B + register prefetch (T14) ----------
__global__ __launch_bounds__(1024, 4)
void cv22_main(const float* __restrict__ img,
               const float* __restrict__ b1,
               const float* __restrict__ b2,
               const unsigned short* __restrict__ txtTh,
               const unsigned short* __restrict__ txtTl,
               const unsigned short* __restrict__ w1Th,
               const unsigned short* __restrict__ w1Tl,
               const unsigned short* __restrict__ w2Th,
               const unsigned short* __restrict__ w2Tl,
               const unsigned* __restrict__ target,
               float* __restrict__ partials)
{
    __shared__ unsigned short YH[2][8192];   // 32 KB A-frag hi per row-group
    __shared__ unsigned short YL[2][8192];   // 32 KB A-frag lo
    __shared__ unsigned short BH[18432];     // 36.9 KB: 256 runs x 72 (64+8 pad) shorts
    __shared__ unsigned short BL[18432];     // 36.9 KB
    __shared__ float red[1024];
    __shared__ float sAr[TM], sMx[TM], sVt[TM];
    __shared__ float srow[TM][2];
    __shared__ int   stgt[TM];
    __shared__ int   tflag;

    unsigned short* hfH = &YH[0][0];       // alias; barriers separate lifetimes
    unsigned short* hfL = &YH[0][4096];

    const int t    = threadIdx.x;
    const int w    = t >> 6;        // wave 0..15
    const int l    = t & 63;
    const int wr   = w >> 3;        // row-group 0/1
    const int wc   = w & 7;         // col-group 0..7
    const int blk  = blockIdx.x;
    const int row0 = blk * TM;

    if (t == 0) {
        int allz = 1, small = 1;
        #pragma unroll 1
        for (int i = 0; i < 32; ++i) {
            allz  &= (target[2 * i + 1] == 0u);
            small &= (target[2 * i] < 1000000u);
        }
        tflag = (allz && small) ? 1 : 0;
    }
    __syncthreads();
    if (t < TM) {
        int r = row0 + t;
        int tg = (int)(tflag ? target[2 * r] : target[r]);
        if (tg < 0) tg = 0;
        if (tg > NN - 1) tg = NN - 1;
        stgt[t] = tg;
    }

    // P1: pack img A-fragments from global (2 k-tiles per wave) [validated]
    #pragma unroll
    for (int s = 0; s < 2; ++s) {
        const int kt = wc * 2 + s;
        const float* ip = img + (size_t)(row0 + wr * 16 + (l & 15)) * DD + kt * 32 + (l >> 4) * 8;
        float4 v0 = *(const float4*)ip;
        float4 v1 = *(const float4*)(ip + 4);
        float xs[8] = {v0.x, v0.y, v0.z, v0.w, v1.x, v1.y, v1.z, v1.w};
        bf8 vh, vl;
        #pragma unroll
        for (int e = 0; e < 8; ++e) {
            unsigned short hh = cv22_f2bf(xs[e]);
            vh[e] = (short)hh;
            vl[e] = (short)cv22_f2bf(xs[e] - cv22_bf2f(hh));
        }
        *(bf8*)&YH[wr][kt * 512 + l * 8] = vh;
        *(bf8*)&YL[wr][kt * 512 + l * 8] = vl;
    }
    __syncthreads();

    // P2: h = relu(img @ w1 + b1) [validated]
    float hv[4];
    {
        f4 acc = {0.f, 0.f, 0.f, 0.f};
        const int jj = wc * 16 + (l & 15);
        const unsigned short* bh = w1Th + (size_t)jj * DD + ((l >> 4) * 8);
        const unsigned short* bl = w1Tl + (size_t)jj * DD + ((l >> 4) * 8);
        #pragma unroll 4
        for (int kt = 0; kt < 16; ++kt) {
            bf8 ah = *(const bf8*)&YH[wr][kt * 512 + l * 8];
            bf8 al = *(const bf8*)&YL[wr][kt * 512 + l * 8];
            bf8 wh = *(const bf8*)(bh + kt * 32);
            bf8 wl = *(const bf8*)(bl + kt * 32);
            acc = MFMA16(ah, wh, acc);
            acc = MFMA16(ah, wl, acc);
            acc = MFMA16(al, wh, acc);
        }
        float bv = b1[jj];
        #pragma unroll
        for (int r = 0; r < 4; ++r) hv[r] = fmaxf(acc[r] + bv, 0.f);
    }
    __syncthreads();

    // P2b: scatter h into hf fragment layout [validated]
    {
        const int jj  = wc * 16 + (l & 15);
        const int kt2 = jj >> 5;
        const int e   = jj & 7;
        const int hi4 = ((jj >> 3) & 3) << 4;
        #pragma unroll
        for (int r = 0; r < 4; ++r) {
            int row16 = (l >> 4) * 4 + r;
            int lane2 = row16 | hi4;
            unsigned short hh = cv22_f2bf(hv[r]);
            hfH[wr * 2048 + kt2 * 512 + lane2 * 8 + e] = hh;
            hfL[wr * 2048 + kt2 * 512 + lane2 * 8 + e] = cv22_f2bf(hv[r] - cv22_bf2f(hh));
        }
    }
    __syncthreads();

    // P3: adapted = relu(h @ w2 + b2); blend with img re-read [validated]
    float blv[4][4];
    {
        const int c15i = l & 15;
        #pragma unroll
        for (int ti = 0; ti < 4; ++ti) {
            const int tix = wc + ti * 8;
            const int jj  = tix * 16 + c15i;
            f4 acc = {0.f, 0.f, 0.f, 0.f};
            const unsigned short* bh = w2Th + (size_t)jj * HH + ((l >> 4) * 8);
            const unsigned short* bl = w2Tl + (size_t)jj * HH + ((l >> 4) * 8);
            #pragma unroll
            for (int kt = 0; kt < 4; ++kt) {
                bf8 ah = *(const bf8*)&hfH[wr * 2048 + kt * 512 + l * 8];
                bf8 al = *(const bf8*)&hfL[wr * 2048 + kt * 512 + l * 8];
                bf8 wh = *(const bf8*)(bh + kt * 32);
                bf8 wl = *(const bf8*)(bl + kt * 32);
                acc = MFMA16(ah, wh, acc);
                acc = MFMA16(ah, wl, acc);
                acc = MFMA16(al, wh, acc);
            }
            float bv = b2[jj];
            #pragma unroll
            for (int r = 0; r < 4; ++r) {
                int row16 = (l >> 4) * 4 + r;
                float iv = img[(size_t)(row0 + wr * 16 + row16) * DD + jj];
                blv[ti][r] = 0.5f * iv + 0.5f * fmaxf(acc[r] + bv, 0.f);
            }
        }
    }
    __syncthreads();

    // P3b: scatter img_adapted into YH/YL [validated]
    {
        const int c15i = l & 15;
        #pragma unroll
        for (int ti = 0; ti < 4; ++ti) {
            const int tix = wc + ti * 8;
            const int jj  = tix * 16 + c15i;
            const int kt  = jj >> 5;
            const int e   = jj & 7;
            const int hi4 = ((jj >> 3) & 3) << 4;
            #pragma unroll
            for (int r = 0; r < 4; ++r) {
                int row16 = (l >> 4) * 4 + r;
                int lane2 = row16 | hi4;
                unsigned short hh = cv22_f2bf(blv[ti][r]);
                YH[wr][kt * 512 + lane2 * 8 + e] = hh;
                YL[wr][kt * 512 + lane2 * 8 + e] = cv22_f2bf(blv[ti][r] - cv22_bf2f(hh));
            }
        }
    }
    __syncthreads();

    // P4: sim via LDS-staged B panel + REGISTER PREFETCH (T14).
    // Chunk order and per-chunk MFMA sequence identical to r21 (bit-identical sim).
    f4 simacc[8];
    #pragma unroll
    for (int i = 0; i < 8; ++i) simacc[i] = (f4){0.f, 0.f, 0.f, 0.f};

    const int runT = t >> 2;        // 0..255 staging run (global col p*256+runT)
    const int part = t & 3;         // 0..3 (32B each of the 128B run-chunk)
    const int c15  = l & 15;
    const int kof  = (l >> 4) * 8;

    bf8 nh0, nh1, nl0, nl1;
    {   // preload + write chunk 0 (p=0, ktc=0); BH/BL first use after P3b barrier
        const size_t g = (size_t)runT * DD + part * 16;
        nh0 = *(const bf8*)(txtTh + g);
        nh1 = *(const bf8*)(txtTh + g + 8);
        nl0 = *(const bf8*)(txtTl + g);
        nl1 = *(const bf8*)(txtTl + g + 8);
        unsigned short* dh = &BH[runT * 72 + part * 16];
        *(bf8*)dh = nh0; *(bf8*)(dh + 8) = nh1;
        unsigned short* dl = &BL[runT * 72 + part * 16];
        *(bf8*)dl = nl0; *(bf8*)(dl + 8) = nl1;
    }
    __syncthreads();   // chunk 0 staged

    #pragma unroll
    for (int p = 0; p < 4; ++p) {
        #pragma unroll 1
        for (int ktc = 0; ktc < 8; ++ktc) {
            // issue next-chunk global loads (latency hides under MFMA below)
            const int nc = p * 8 + ktc + 1;
            const bool have_next = (nc < 32);
            if (have_next) {
                const int np = nc >> 3, nk = nc & 7;
                const size_t g = (size_t)(np * 256 + runT) * DD + nk * 64 + part * 16;
                nh0 = *(const bf8*)(txtTh + g);
                nh1 = *(const bf8*)(txtTh + g + 8);
                nl0 = *(const bf8*)(txtTl + g);
                nl1 = *(const bf8*)(txtTl + g + 8);
            }
            // MFMA on current chunk (reads BH/BL + YH/YL)
            #pragma unroll
            for (int ktl = 0; ktl < 2; ++ktl) {
                const int kt = ktc * 2 + ktl;   // global k-tile 0..15
                bf8 ah = *(const bf8*)&YH[wr][kt * 512 + l * 8];
                bf8 al = *(const bf8*)&YL[wr][kt * 512 + l * 8];
                const int runA = wc * 16 + c15;          // local tile wc
                const int runB = (wc + 8) * 16 + c15;    // local tile wc+8
                bf8 bAh = *(const bf8*)&BH[runA * 72 + ktl * 32 + kof];
                bf8 bAl = *(const bf8*)&BL[runA * 72 + ktl * 32 + kof];
                bf8 bBh = *(const bf8*)&BH[runB * 72 + ktl * 32 + kof];
                bf8 bBl = *(const bf8*)&BL[runB * 72 + ktl * 32 + kof];
                simacc[p * 2]     = MFMA16(ah, bAh, simacc[p * 2]);
                simacc[p * 2 + 1] = MFMA16(ah, bBh, simacc[p * 2 + 1]);
                simacc[p * 2]     = MFMA16(ah, bAl, simacc[p * 2]);
                simacc[p * 2 + 1] = MFMA16(ah, bBl, simacc[p * 2 + 1]);
                simacc[p * 2]     = MFMA16(al, bAh, simacc[p * 2]);
                simacc[p * 2 + 1] = MFMA16(al, bBh, simacc[p * 2 + 1]);
            }
            __syncthreads();   // current chunk's LDS reads complete
            if (have_next) {   // write prefetched chunk (vmcnt wait lands here)
                unsigned short* dh = &BH[runT * 72 + part * 16];
                *(bf8*)dh = nh0; *(bf8*)(dh + 8) = nh1;
                unsigned short* dl = &BL[runT * 72 + part * 16];
                *(bf8*)dl = nl0; *(bf8*)(dl + 8) = nl1;
            }
            __syncthreads();   // staged data visible
        }
    }

    // ---- epilogue from registers [r20/r21-validated; same tix formula] ----
    float s2v[4] = {0.f, 0.f, 0.f, 0.f};
    float mxv[4] = {-1e30f, -1e30f, -1e30f, -1e30f};
    float vtv[4] = {-1e30f, -1e30f, -1e30f, -1e30f};
    int   mxi[4] = {0x7fffffff, 0x7fffffff, 0x7fffffff, 0x7fffffff};

    #pragma unroll
    for (int i = 0; i < 8; ++i) {
        const int tix = wc + (i >> 1) * 16 + (i & 1) * 8;
        const int col = tix * 16 + (l & 15);
        const bool ok = col < NN;
        #pragma unroll
        for (int r = 0; r < 4; ++r) {
            float v = simacc[i][r];
            if (ok) {
                s2v[r] += v * v;
                if (v > mxv[r] || (v == mxv[r] && col < mxi[r])) { mxv[r] = v; mxi[r] = col; }
                int R = wr * 16 + (l >> 4) * 4 + r;
                if (col == stgt[R]) vtv[r] = v;
            }
        }
    }
    #pragma unroll
    for (int m = 1; m < 16; m <<= 1) {
        #pragma unroll
        for (int r = 0; r < 4; ++r) {
            s2v[r] += __shfl_xor(s2v[r], m);
            float ov = __shfl_xor(mxv[r], m);
            int   oi = __shfl_xor(mxi[r], m);
            if (ov > mxv[r] || (ov == mxv[r] && oi < mxi[r])) { mxv[r] = ov; mxi[r] = oi; }
            vtv[r] = fmaxf(vtv[r], __shfl_xor(vtv[r], m));
        }
    }
    if ((l & 15) == 0) {
        #pragma unroll
        for (int r = 0; r < 4; ++r) {
            int R = wr * 16 + (l >> 4) * 4 + r;
            red[  0 + R * 8 + wc] = s2v[r];
            red[256 + R * 8 + wc] = mxv[r];
            red[512 + R * 8 + wc] = __int_as_float(mxi[r]);
            red[768 + R * 8 + wc] = vtv[r];
        }
    }
    __syncthreads();
    if (t < TM) {
        float S2 = 0.f, MX = -1e30f, VT = -1e30f;
        int MI = 0x7fffffff;
        #pragma unroll
        for (int ww = 0; ww < 8; ++ww) {
            S2 += red[t * 8 + ww];
            float ov = red[256 + t * 8 + ww];
            int   oi = __float_as_int(red[512 + t * 8 + ww]);
            if (ov > MX || (ov == MX && oi < MI)) { MX = ov; MI = oi; }
            VT = fmaxf(VT, red[768 + t * 8 + ww]);
        }
        sAr[t] = 1.0f / sqrtf(S2);
        sMx[t] = MX;
        sVt[t] = VT;
        srow[t][1] = (MI == stgt[t]) ? 1.f : 0.f;
    }
    __syncthreads();

    float es[4] = {0.f, 0.f, 0.f, 0.f};
    #pragma unroll
    for (int i = 0; i < 8; ++i) {
        const int tix = wc + (i >> 1) * 16 + (i & 1) * 8;
        const int col = tix * 16 + (l & 15);
        const bool ok = col < NN;
        #pragma unroll
        for (int r = 0; r < 4; ++r) {
            if (ok) {
                int R = wr * 16 + (l >> 4) * 4 + r;
                es[r] += expf((simacc[i][r] - sMx[R]) * sAr[R]);
            }
        }
    }
    #pragma unroll
    for (int m = 1; m < 16; m <<= 1) {
        #pragma unroll
        for (int r = 0; r < 4; ++r) es[r] += __shfl_xor(es[r], m);
    }
    if ((l & 15) == 0) {
        #pragma unroll
        for (int r = 0; r < 4; ++r) {
            int R = wr * 16 + (l >> 4) * 4 + r;
            red[R * 8 + wc] = es[r];
        }
    }
    __syncthreads();
    if (t < TM) {
        float E = 0.f;
        #pragma unroll
        for (int ww = 0; ww < 8; ++ww) E += red[t * 8 + ww];
        srow[t][0] = (sMx[t] - sVt[t]) * sAr[t] + logf(E);
    }
    __syncthreads();
    if (t == 0) {
        float ls = 0.f, ac = 0.f;
        #pragma unroll
        for (int r = 0; r < TM; ++r) { ls += srow[r][0]; ac += srow[r][1]; }
        partials[blk * 2 + 0] = ls;
        partials[blk * 2 + 1] = ac;
    }
}

__global__ __launch_bounds__(256)
void cv22_final(const float* __restrict__ partials, int nblk, float* __restrict__ out)
{
    __shared__ float fb[512];
    float ls = 0.f, ac = 0.f;
    #pragma unroll 1
    for (int i = threadIdx.x; i < nblk; i += 256) {
        ls += partials[2 * i];
        ac += partials[2 * i + 1];
    }
    fb[threadIdx.x] = ls;
    fb[256 + threadIdx.x] = ac;
    __syncthreads();
    if (threadIdx.x == 0) {
        float L = 0.f, A = 0.f;
        for (int i = 0; i < 256; ++i) { L += fb[i]; A += fb[256 + i]; }
        out[0] = L * (1.0f / (float)BSZ);   // mean NLL (validated)
        out[1] = A;                          // accuracy count (validated)
    }
}

// ---------- fallback: validated fp32 path (r14) ----------
__global__ __launch_bounds__(256)
void cv22_fb_main(const float* __restrict__ img, const float* __restrict__ txt,
                  const float* __restrict__ w1, const float* __restrict__ b1,
                  const float* __restrict__ w2, const float* __restrict__ b2,
                  const unsigned* __restrict__ target, float* __restrict__ partials)
{
    __shared__ __align__(16) float arena[16000];
    __shared__ float red[256];
    __shared__ float smax[FBTM], sA[FBTM], srow[FBTM][2];
    __shared__ int   stgt[FBTM], sargmax[FBTM], tflag;

    const int t = threadIdx.x, blk = blockIdx.x, row0 = blk * FBTM;
    if (t == 0) {
        int allz = 1, small = 1;
        #pragma unroll 1
        for (int i = 0; i < 32; ++i) { allz &= (target[2*i+1]==0u); small &= (target[2*i]<1000000u); }
        tflag = (allz && small) ? 1 : 0;
    }
    __syncthreads();
    if (t < FBTM) {
        int r = row0 + t;
        int tg = (int)(tflag ? target[2*r] : target[r]);
        stgt[t] = tg < 0 ? 0 : (tg > NN-1 ? NN-1 : tg);
    }
    float* simg = arena; float* sh = arena + 8192;
    {
        const float4* src = (const float4*)(img + (size_t)row0 * DD);
        float4* dst = (float4*)simg;
        #pragma unroll
        for (int i = 0; i < 8; ++i) dst[t + i*256] = src[t + i*256];
    }
    __syncthreads();
    {
        const int c = t & 127, rh = t >> 7;
        float acc[8];
        #pragma unroll
        for (int i = 0; i < 8; ++i) acc[i] = 0.f;
        #pragma unroll 1
        for (int k = 0; k < DD; k += 4) {
            float w0=w1[(k+0)*HH+c], w1_=w1[(k+1)*HH+c], w2_=w1[(k+2)*HH+c], w3=w1[(k+3)*HH+c];
            #pragma unroll
            for (int i = 0; i < 8; ++i) {
                const float4 s = *(const float4*)&simg[(rh*8+i)*DD + k];
                acc[i] = fmaf(s.x,w0,fmaf(s.y,w1_,fmaf(s.z,w2_,fmaf(s.w,w3,acc[i]))));
            }
        }
        float bb = b1[c];
        #pragma unroll
        for (int i = 0; i < 8; ++i) sh[(rh*8+i)*HH + c] = fmaxf(acc[i]+bb, 0.f);
    }
    __syncthreads();
    {
        const int c0 = t, c1 = t + 256;
        float accA[FBTM], accB[FBTM];
        #pragma unroll
        for (int r = 0; r < FBTM; ++r) { accA[r]=0.f; accB[r]=0.f; }
        #pragma unroll 1
        for (int k = 0; k < HH; k += 4) {
            float wa[4], wb[4];
            #pragma unroll
            for (int u = 0; u < 4; ++u) { wa[u]=w2[(k+u)*DD+c0]; wb[u]=w2[(k+u)*DD+c1]; }
            #pragma unroll
            for (int r = 0; r < FBTM; ++r) {
                const float4 hv = *(const float4*)&sh[r*HH + k];
                accA[r]=fmaf(hv.x,wa[0],fmaf(hv.y,wa[1],fmaf(hv.z,wa[2],fmaf(hv.w,wa[3],accA[r]))));
                accB[r]=fmaf(hv.x,wb[0],fmaf(hv.y,wb[1],fmaf(hv.z,wb[2],fmaf(hv.w,wb[3],accB[r]))));
            }
        }
        const float ba = b2[c0], bb = b2[c1];
        #pragma unroll
        for (int r = 0; r < FBTM; ++r) {
            simg[r*DD+c0] = 0.5f*simg[r*DD+c0] + 0.5f*fmaxf(accA[r]+ba, 0.f);
            simg[r*DD+c1] = 0.5f*simg[r*DD+c1] + 0.5f*fmaxf(accB[r]+bb, 0.f);
        }
    }
    __syncthreads();
    float acc4[4][FBTM];
    #pragma unroll
    for (int c = 0; c < 4; ++c)
        #pragma unroll
        for (int r = 0; r < FBTM; ++r) acc4[c][r] = 0.f;
    const bool v3 = (768 + t) < NN;
    #pragma unroll 1
    for (int k = 0; k < DD; k += 4) {
        float tx[4][4];
        #pragma unroll
        for (int u = 0; u < 4; ++u) {
            const float* tp = txt + (size_t)(k+u)*NN;
            tx[0][u]=tp[t]; tx[1][u]=tp[256+t]; tx[2][u]=tp[512+t]; tx[3][u]=v3?tp[768+t]:0.f;
        }
        #pragma unroll
        for (int half = 0; half < 2; ++half) {
            float4 sv[8];
            #pragma unroll
            for (int i = 0; i < 8; ++i) sv[i] = *(const float4*)&simg[(half*8+i)*DD + k];
            #pragma unroll
            for (int i = 0; i < 8; ++i) {
                const int r = half*8 + i;
                #pragma unroll
                for (int c = 0; c < 4; ++c)
                    acc4[c][r]=fmaf(sv[i].x,tx[c][0],fmaf(sv[i].y,tx[c][1],fmaf(sv[i].z,tx[c][2],fmaf(sv[i].w,tx[c][3],acc4[c][r]))));
            }
        }
    }
    __syncthreads();
    #pragma unroll
    for (int c = 0; c < 4; ++c) {
        const int col = c*256 + t;
        if (col < NN)
            #pragma unroll
            for (int r = 0; r < FBTM; ++r) arena[r*NN + col] = acc4[c][r];
    }
    __syncthreads();
    const int myrow = t >> 4, ln = t & 15, tgt = stgt[myrow];
    {
        float S2 = 0.f;
        #pragma unroll 1
        for (int q = 0; q < 63; ++q) { int j = ln + (q<<4); if (j < NN) { float v = arena[myrow*NN+j]; S2 += v*v; } }
        red[t] = S2; __syncthreads();
        if (ln == 0) { float s=0.f; for (int i=0;i<16;++i) s+=red[myrow*16+i]; sA[myrow]=1.0f/sqrtf(s); }
        __syncthreads();
    }
    const float a = sA[myrow];
    #pragma unroll 1
    for (int q = 0; q < 63; ++q) { int j = ln + (q<<4); if (j < NN) arena[myrow*NN+j] *= a; }
    __syncthreads();
    if (t < FBTM) {
        const float* rp = &arena[t*NN];
        float bm = rp[0]; int bi = 0;
        #pragma unroll 4
        for (int j = 1; j < NN; ++j) { float v = rp[j]; if (v > bm) { bm = v; bi = j; } }
        sargmax[t] = bi;
    }
    __syncthreads();
    float mx = -1e30f, vtl = -1e30f;
    #pragma unroll 1
    for (int q = 0; q < 63; ++q) {
        int j = ln + (q<<4);
        if (j < NN) { float v = arena[myrow*NN+j]; mx = fmaxf(mx, v); if (j == tgt) vtl = v; }
    }
    red[t] = mx; __syncthreads();
    float rowmax = -1e30f;
    if (ln == 0) { for (int i=0;i<16;++i) rowmax = fmaxf(rowmax, red[myrow*16+i]); smax[myrow] = rowmax; }
    __syncthreads();
    rowmax = smax[myrow];
    red[t] = vtl; __syncthreads();
    float vt = -1e30f;
    if (ln == 0) { for (int i=0;i<16;++i) vt = fmaxf(vt, red[myrow*16+i]); }
    __syncthreads();
    float E = 0.f;
    #pragma unroll 1
    for (int q = 0; q < 63; ++q) { int j = ln + (q<<4); if (j < NN) E += expf(arena[myrow*NN+j] - rowmax); }
    red[t] = E; __syncthreads();
    if (ln == 0) {
        float Er = 0.f; for (int i=0;i<16;++i) Er += red[myrow*16+i];
        srow[myrow][0] = (rowmax - vt) + logf(Er);
        srow[myrow][1] = (sargmax[myrow] == tgt) ? 1.f : 0.f;
    }
    __syncthreads();
    if (t == 0) {
        float ls = 0.f, ac = 0.f;
        #pragma unroll
        for (int r = 0; r < FBTM; ++r) { ls += srow[r][0]; ac += srow[r][1]; }
        partials[blk*2+0] = ls; partials[blk*2+1] = ac;
    }
}

extern "C" void kernel_launch(void* const* d_in, const int* in_sizes, int n_in,
                              void* d_out, int out_size, void* d_ws, size_t ws_size,
                              hipStream_t stream)
{
    const void *img = nullptr, *txt = nullptr, *w1 = nullptr, *w2 = nullptr;
    const void *b1 = nullptr, *b2 = nullptr, *tgt = nullptr;
    for (int i = 0; i < n_in; ++i) {
        long s = in_sizes[i];
        if      (s == (long)BSZ * DD) img = d_in[i];
        else if (s == (long)DD * NN)  txt = d_in[i];
        else if (s == (long)DD * HH) { if (!w1) w1 = d_in[i]; else w2 = d_in[i]; }
        else if (s == HH)  b1 = d_in[i];
        else if (s == DD)  b2 = d_in[i];
        else if (s == BSZ) tgt = d_in[i];
    }
    if (!img || !txt || !w1 || !w2 || !b1 || !b2 || !tgt) {
        img = d_in[0]; txt = d_in[1]; w1 = d_in[2]; b1 = d_in[3];
        w2 = d_in[4]; b2 = d_in[5]; tgt = d_in[8];
    }

    const size_t nTxt = (size_t)1024 * 512, nW = (size_t)128 * 512;
    const size_t needBytes = (2 * nTxt + 4 * nW) * 2 + 16384 + 256;

    if (ws_size >= needBytes) {
        unsigned short* txtTh = (unsigned short*)d_ws;
        unsigned short* txtTl = txtTh + nTxt;
        unsigned short* w1Th  = txtTl + nTxt;
        unsigned short* w1Tl  = w1Th + nW;
        unsigned short* w2Th  = w1Tl + nW;
        unsigned short* w2Tl  = w2Th + nW;
        float* partials = (float*)(w2Tl + nW);

        cv22_prep_txt<<<1024, 256, 0, stream>>>((const float*)txt, txtTh, txtTl);
        cv22_prep_w1<<<128, 256, 0, stream>>>((const float*)w1, w1Th, w1Tl);
        cv22_prep_w2<<<512, 128, 0, stream>>>((const float*)w2, w2Th, w2Tl);
        cv22_main<<<NBLK, 1024, 0, stream>>>((const float*)img, (const float*)b1,
                                             (const float*)b2, txtTh, txtTl,
                                             w1Th, w1Tl, w2Th, w2Tl,
                                             (const unsigned*)tgt, partials);
        cv22_final<<<1, 256, 0, stream>>>(partials, NBLK, (float*)d_out);
    } else {
        float* partials = (float*)d_ws;
        cv22_fb_main<<<FBBLK, 256, 0, stream>>>((const float*)img, (const float*)txt,
                                                (const float*)w1, (const float*)b1,
                                                (const float*)w2, (const float*)b2,
                                                (const unsigned*)tgt, partials);
        cv22_final<<<1, 256, 0, stream>>>(partials, FBBLK, (float*)d_out);
    }
}